// Round 5
// baseline (216.536 us; speedup 1.0000x reference)
//
#include <hip/hip_runtime.h>
#include <hip/hip_bf16.h>
#include <cstddef>

typedef __hip_bfloat16 bf16;
typedef __attribute__((ext_vector_type(8))) short bf16x8;   // MFMA A/B frag
typedef __attribute__((ext_vector_type(4))) float f32x4;    // MFMA C/D frag
typedef __attribute__((ext_vector_type(4))) short short4v;  // 4x bf16 packed

__device__ __forceinline__ float b2f(bf16 v) { return __bfloat162float(v); }
__device__ __forceinline__ bf16 f2b(float v) { return __float2bfloat16(v); }

#define MFMA(a, b, c) __builtin_amdgcn_mfma_f32_16x16x32_bf16((a), (b), (c), 0, 0, 0)

// Convert 8 consecutive fp32 -> bf16x8 (rn, same rounding as old prep pass).
__device__ __forceinline__ bf16x8 cvt8f(const float* p) {
  const float4 a = *(const float4*)p;
  const float4 b = *(const float4*)(p + 4);
  union { __hip_bfloat162 h2[4]; bf16x8 v; } u;
  u.h2[0] = __float22bfloat162_rn(float2{a.x, a.y});
  u.h2[1] = __float22bfloat162_rn(float2{a.z, a.w});
  u.h2[2] = __float22bfloat162_rn(float2{b.x, b.y});
  u.h2[3] = __float22bfloat162_rn(float2{b.z, b.w});
  return u.v;
}

// Global x row (16384 rows: [a=0: x0 8192][a=1: x1 8192], row-major C=256).
__device__ __forceinline__ const float* xrow_ptr(
    const float* x0, const float* x1, int rr) {
  return (rr < 8192) ? (x0 + rr * 256) : (x1 + (rr - 8192) * 256);
}

// W-tile staging from fp32: 64 rows x 256 K into LDS [64][264] (pad 264),
// convert-during-stage. Coalesced 32 B per thread.
#define STAGE_WF(W_lds, wgl, ldg)                                            \
  _Pragma("unroll")                                                          \
  for (int uu_ = 0; uu_ < 8; ++uu_) {                                        \
    const int idx_ = uu_ * 256 + t;                                          \
    const int wr_ = idx_ >> 5;                                               \
    const int wc_ = (idx_ & 31) * 8;                                         \
    *(bf16x8*)&W_lds[wr_][wc_] = cvt8f((wgl) + wr_ * (ldg) + wc_);           \
  }

// Wsr staging (per p): W'[o][c] = Wsr[o*1024 + c*4 + p]; dword gather at
// 16 B stride (L2-resident), convert-during-stage.
#define STAGE_WSR(W_lds, Wsr, colh, p)                                       \
  _Pragma("unroll")                                                          \
  for (int uu_ = 0; uu_ < 8; ++uu_) {                                        \
    const int idx_ = uu_ * 256 + t;                                          \
    const int wr_ = idx_ >> 5;                                               \
    const int wc_ = (idx_ & 31) * 8;                                         \
    const float* wp_ = (Wsr) + ((colh) + wr_) * 1024 + wc_ * 4 + (p);        \
    union { __hip_bfloat162 h2[4]; bf16x8 v; } u_;                           \
    u_.h2[0] = __float22bfloat162_rn(float2{wp_[0],  wp_[4]});               \
    u_.h2[1] = __float22bfloat162_rn(float2{wp_[8],  wp_[12]});              \
    u_.h2[2] = __float22bfloat162_rn(float2{wp_[16], wp_[20]});              \
    u_.h2[3] = __float22bfloat162_rn(float2{wp_[24], wp_[28]});              \
    *(bf16x8*)&W_lds[wr_][wc_] = u_.v;                                       \
  }

// ---------------------------------------------------------------------------
// Kernel 1 (fused): blocks x<256: q = (x @ Wq^T) * scale' -> bf16.
//                   blocks x>=256: conv as 4 p-passes of 256-K MFMA GEMM.
// x read directly as fp32 (in-register cvt); W staged from fp32.
// grid (320,4). scale' folds log2(e) so attention uses raw v_exp_f32.
// ---------------------------------------------------------------------------
__global__ __launch_bounds__(256) void qc_mfma(
    const float* __restrict__ x0, const float* __restrict__ x1,
    const float* __restrict__ Wq, const float* __restrict__ Wsr,
    const float* __restrict__ bsr, bf16* __restrict__ q,
    bf16* __restrict__ xsb) {
  __shared__ bf16 W_lds[64][264];
  const int t = threadIdx.x;
  const int wave = t >> 6, lane = t & 63, quad = lane >> 4, l16 = lane & 15;
  const int colh = blockIdx.y * 64;

  if (blockIdx.x < 256) {
    // ---- q-projection body ----
    const int row0 = blockIdx.x * 64 + wave * 16;
    STAGE_WF(W_lds, Wq + colh * 256, 256);
    __syncthreads();
    const float* ap = xrow_ptr(x0, x1, row0 + l16) + quad * 8;
    f32x4 acc[4];
    #pragma unroll
    for (int j = 0; j < 4; ++j) acc[j] = (f32x4){0.f, 0.f, 0.f, 0.f};
    #pragma unroll
    for (int k0 = 0; k0 < 256; k0 += 32) {
      const bf16x8 af = cvt8f(ap + k0);
      #pragma unroll
      for (int j = 0; j < 4; ++j) {
        const bf16x8 wf = *(const bf16x8*)&W_lds[j * 16 + l16][k0 + quad * 8];
        acc[j] = MFMA(af, wf, acc[j]);
      }
    }
    const float scale = 0.2550348572f;  // log2(e)/sqrt(32)
    #pragma unroll
    for (int j = 0; j < 4; ++j)
      #pragma unroll
      for (int r = 0; r < 4; ++r)
        q[(row0 + quad * 4 + r) * 256 + colh + j * 16 + l16] =
            f2b(acc[j][r] * scale);
  } else {
    // ---- conv body ----
    const int bx = blockIdx.x - 256;
    const int row0 = bx * 64 + wave * 16;
    const int mrow = row0 + l16;
    const int ab = mrow >> 10;
    const int m = mrow & 1023;
    const int mi_ = m >> 5, mj = m & 31;
    f32x4 acc[4];
    #pragma unroll
    for (int j = 0; j < 4; ++j) acc[j] = (f32x4){0.f, 0.f, 0.f, 0.f};
    for (int p = 0; p < 4; ++p) {
      __syncthreads();   // protect previous pass's W_lds reads
      STAGE_WSR(W_lds, Wsr, colh, p);
      __syncthreads();
      const int n = (2 * mi_ + (p >> 1)) * 64 + 2 * mj + (p & 1);
      const float* ap = xrow_ptr(x0, x1, ab * 4096 + n) + quad * 8;
      #pragma unroll
      for (int c0 = 0; c0 < 256; c0 += 32) {
        const bf16x8 af = cvt8f(ap + c0);
        #pragma unroll
        for (int j = 0; j < 4; ++j) {
          const bf16x8 wf = *(const bf16x8*)&W_lds[j * 16 + l16][c0 + quad * 8];
          acc[j] = MFMA(af, wf, acc[j]);
        }
      }
    }
    #pragma unroll
    for (int j = 0; j < 4; ++j) {
      const int col = colh + j * 16 + l16;
      const float bv = bsr[col];
      #pragma unroll
      for (int r = 0; r < 4; ++r)
        xsb[(row0 + quad * 4 + r) * 256 + col] = f2b(acc[j][r] + bv);
    }
  }
}

// ---------------------------------------------------------------------------
// Kernel 2 (fused LN + kv): LayerNorm over C=256 in-register (quad-reduce
// via shfl_xor 16/32), then kv = ln(xsb) @ Wkv^T (W staged from fp32).
// K-half -> kbuf [abh][m][d]; V-half -> vbuf_t [abh][d][m'] with the bit
// permutation m' = (m&~63) | km(m&63),
//   km(j) = (j&32) | ((j&12)<<1) | ((j&16)>>2) | (j&3),
// so the swapped-QK attention's P fragments are lane-local. grid (64, 8).
// ---------------------------------------------------------------------------
__global__ __launch_bounds__(256) void kvln_mfma(
    const bf16* __restrict__ xsb, const float* __restrict__ Wkv,
    const float* __restrict__ w0, const float* __restrict__ b0,
    const float* __restrict__ w1, const float* __restrict__ b1,
    bf16* __restrict__ kbuf, bf16* __restrict__ vbuf_t) {
  __shared__ bf16 W_lds[64][264];
  __shared__ float lnw[256], lnb[256];
  const int t = threadIdx.x;
  const int wave = t >> 6, lane = t & 63, quad = lane >> 4, l16 = lane & 15;
  const int row0 = blockIdx.x * 64 + wave * 16;
  const int colh = blockIdx.y * 64;     // 0..448 over O=512
  const int a = (blockIdx.x * 64) >> 11;   // block-uniform LN param select
  lnw[t] = a ? w1[t] : w0[t];
  lnb[t] = a ? b1[t] : b0[t];
  STAGE_WF(W_lds, Wkv + colh * 256, 256);
  __syncthreads();

  const bf16* ap = xsb + (row0 + l16) * 256 + quad * 8;
  bf16x8 af[8];
  float sum = 0.f, ss = 0.f;
  #pragma unroll
  for (int i = 0; i < 8; ++i) {
    af[i] = *(const bf16x8*)(ap + i * 32);
    #pragma unroll
    for (int e = 0; e < 8; ++e) {
      const float x = b2f(((bf16*)&af[i])[e]);
      sum += x; ss += x * x;
    }
  }
  sum += __shfl_xor(sum, 16, 64); sum += __shfl_xor(sum, 32, 64);
  ss  += __shfl_xor(ss, 16, 64);  ss  += __shfl_xor(ss, 32, 64);
  const float mu = sum * (1.0f / 256.0f);
  const float var = ss * (1.0f / 256.0f) - mu * mu;
  const float rstd = rsqrtf(var + 1e-5f);
  #pragma unroll
  for (int i = 0; i < 8; ++i) {
    const int cb = i * 32 + quad * 8;
    union { bf16 h[8]; bf16x8 v; } u;
    #pragma unroll
    for (int e = 0; e < 8; ++e) {
      const float x = b2f(((bf16*)&af[i])[e]);
      u.h[e] = f2b((x - mu) * rstd * lnw[cb + e] + lnb[cb + e]);
    }
    af[i] = u.v;
  }

  f32x4 acc[4];
  #pragma unroll
  for (int j = 0; j < 4; ++j) acc[j] = (f32x4){0.f, 0.f, 0.f, 0.f};
  #pragma unroll
  for (int i = 0; i < 8; ++i) {
    #pragma unroll
    for (int j = 0; j < 4; ++j) {
      const bf16x8 wf = *(const bf16x8*)&W_lds[j * 16 + l16][i * 32 + quad * 8];
      acc[j] = MFMA(af[i], wf, acc[j]);
    }
  }
  #pragma unroll
  for (int j = 0; j < 4; ++j) {
    const int o = colh + j * 16 + l16;   // 0..511
    #pragma unroll
    for (int r = 0; r < 4; ++r) {
      const int row = row0 + quad * 4 + r;
      const int m = row & 1023;
      const bf16 val = f2b(acc[j][r]);
      if (o < 256) {
        const int h = o >> 5, d = o & 31;
        kbuf[((row >> 10) * 8 + h) * 32768 + m * 32 + d] = val;
      } else {
        const int o2 = o - 256;
        const int h = o2 >> 5, d = o2 & 31;
        const int rr = m & 63;
        const int mp = (m & ~63) | (rr & 32) | ((rr & 12) << 1) |
                       ((rr & 16) >> 2) | (rr & 3);
        vbuf_t[((row >> 10) * 8 + h) * 32768 + d * 1024 + mp] = val;
      }
    }
  }
}

// ---------------------------------------------------------------------------
// Kernel 3: MFMA flash attention, LDS-staged K/V (double-buffered), swapped
// QK^T (S^T = K x Q) with lane-local in-register P -> PV fragments.
// VT is stored XOR-swizzled (octet u -> u ^ ((u>>3)&7)) on both the ds_write
// and ds_read side: spreads the PV B-fragment reads across all 8 bank
// groups (was 16 lanes on 4 groups = 2x LDS serialization).
// q is pre-scaled by log2(e)/sqrt(d) -> softmax uses raw v_exp_f32.
// ---------------------------------------------------------------------------
__global__ __launch_bounds__(256) void attn_mfma(
    const bf16* __restrict__ q, const bf16* __restrict__ kbuf,
    const bf16* __restrict__ vbuf_t, bf16* __restrict__ att) {
  const int abh = blockIdx.y;
  const int ab = abh >> 3;
  const int h = abh & 7;
  const int t = threadIdx.x;
  const int lane = t & 63, quad = lane >> 4, l16 = lane & 15;
  const int qbase = blockIdx.x * 128 + (t >> 6) * 32;

  __shared__ bf16 KT[2][2048];
  __shared__ bf16 VT[2][2048];

  const bf16* kb = kbuf + abh * 32768;
  const bf16* vb = vbuf_t + abh * 32768;

  const int kg = (t >> 6) * 512 + ((t >> 2) & 15) * 32 + (t & 3) * 8;
  const int vg_row = (t >> 7) * 16 + ((t >> 3) & 15);
  const int vg_col = ((t >> 2) & 1) * 32 + (t & 3) * 8;
  const int vt_w = (t ^ ((t >> 3) & 7)) * 8;   // swizzled VT write octet

  bf16x8 qf[2];
  #pragma unroll
  for (int s = 0; s < 2; ++s)
    qf[s] = *(const bf16x8*)(
        q + (ab * 4096 + qbase + s * 16 + l16) * 256 + h * 32 + quad * 8);

  {
    const bf16x8 kr = *(const bf16x8*)(kb + kg);
    const bf16x8 vr = *(const bf16x8*)(vb + vg_row * 1024 + vg_col);
    *(bf16x8*)&KT[0][t * 8] = kr;
    *(bf16x8*)&VT[0][vt_w] = vr;
  }
  __syncthreads();

  f32x4 o[2][2];
  float lp[2] = {0.f, 0.f};
  #pragma unroll
  for (int s = 0; s < 2; ++s) {
    o[s][0] = (f32x4){0.f, 0.f, 0.f, 0.f};
    o[s][1] = (f32x4){0.f, 0.f, 0.f, 0.f};
  }
  const f32x4 zero = {0.f, 0.f, 0.f, 0.f};

  for (int kt = 0; kt < 16; ++kt) {
    const int cur = kt & 1;
    bf16x8 kr, vr;
    const bool pf = (kt + 1 < 16);
    if (pf) {
      const int nk0 = (kt + 1) * 64;
      kr = *(const bf16x8*)(kb + nk0 * 32 + kg);
      vr = *(const bf16x8*)(vb + vg_row * 1024 + nk0 + vg_col);
    }
    // S^T[key][q]: A = K-frag (row=key), B = Q-frag (col=q=l16).
    f32x4 S[2][4];
    #pragma unroll
    for (int tt = 0; tt < 4; ++tt) {
      const bf16x8 kf =
          *(const bf16x8*)&KT[cur][(tt * 64 + l16 * 4 + quad) * 8];
      S[0][tt] = MFMA(kf, qf[0], zero);
      S[1][tt] = MFMA(kf, qf[1], zero);
    }
    // In-register softmax numerator + lane-local PV A-fragments.
    bf16x8 pa[2][2];
    #pragma unroll
    for (int s = 0; s < 2; ++s) {
      float p[4][4];
      float acc = 0.f;
      #pragma unroll
      for (int tt = 0; tt < 4; ++tt)
        #pragma unroll
        for (int r = 0; r < 4; ++r) {
          p[tt][r] = __builtin_amdgcn_exp2f(S[s][tt][r]);
          acc += p[tt][r];
        }
      lp[s] += acc;
      #pragma unroll
      for (int c2 = 0; c2 < 2; ++c2) {
        union { __hip_bfloat162 h2[4]; bf16x8 v; } u;
        u.h2[0] = __float22bfloat162_rn(float2{p[c2 * 2][0], p[c2 * 2][1]});
        u.h2[1] = __float22bfloat162_rn(float2{p[c2 * 2][2], p[c2 * 2][3]});
        u.h2[2] = __float22bfloat162_rn(float2{p[c2 * 2 + 1][0], p[c2 * 2 + 1][1]});
        u.h2[3] = __float22bfloat162_rn(float2{p[c2 * 2 + 1][2], p[c2 * 2 + 1][3]});
        pa[s][c2] = u.v;
      }
    }
    #pragma unroll
    for (int c2 = 0; c2 < 2; ++c2) {
      #pragma unroll
      for (int dh = 0; dh < 2; ++dh) {
        const int vti =
            ((dh * 128 + l16 * 8 + c2 * 4 + quad) ^ (l16 & 7)) * 8;
        const bf16x8 vf = *(const bf16x8*)&VT[cur][vti];
        o[0][dh] = MFMA(pa[0][c2], vf, o[0][dh]);
        o[1][dh] = MFMA(pa[1][c2], vf, o[1][dh]);
      }
    }
    if (pf) {
      *(bf16x8*)&KT[cur ^ 1][t * 8] = kr;
      *(bf16x8*)&VT[cur ^ 1][vt_w] = vr;
    }
    __syncthreads();
  }
  // Denominator: sum across quads (lane ^16, ^32), broadcast, normalize.
  #pragma unroll
  for (int s = 0; s < 2; ++s) {
    lp[s] += __shfl_xor(lp[s], 16, 64);
    lp[s] += __shfl_xor(lp[s], 32, 64);
  }
  #pragma unroll
  for (int s = 0; s < 2; ++s) {
    #pragma unroll
    for (int r = 0; r < 4; ++r) {
      const float li = __shfl(lp[s], quad * 4 + r, 16);
      const float inv = 1.0f / li;
      const int qrow = ab * 4096 + qbase + s * 16 + quad * 4 + r;
      bf16* orow = att + qrow * 256 + h * 32;
      orow[l16]      = f2b(o[s][0][r] * inv);
      orow[16 + l16] = f2b(o[s][1][r] * inv);
    }
  }
}

// ---------------------------------------------------------------------------
// Kernel 4: y = att @ Wproj^T + bproj -> fp32 d_out (W staged from fp32).
// grid (256, 4).
// ---------------------------------------------------------------------------
__global__ __launch_bounds__(256) void proj_mfma(
    const bf16* __restrict__ att, const float* __restrict__ Wp,
    const float* __restrict__ bp, float* __restrict__ outp) {
  __shared__ bf16 W_lds[64][264];
  const int t = threadIdx.x;
  const int wave = t >> 6, lane = t & 63, quad = lane >> 4, l16 = lane & 15;
  const int row0 = blockIdx.x * 64 + wave * 16;
  const int colh = blockIdx.y * 64;
  STAGE_WF(W_lds, Wp + colh * 256, 256);
  __syncthreads();
  const bf16* ap = att + (row0 + l16) * 256 + quad * 8;
  f32x4 acc[4];
  #pragma unroll
  for (int j = 0; j < 4; ++j) acc[j] = (f32x4){0.f, 0.f, 0.f, 0.f};
  #pragma unroll
  for (int k0 = 0; k0 < 256; k0 += 32) {
    const bf16x8 af = *(const bf16x8*)(ap + k0);
    #pragma unroll
    for (int j = 0; j < 4; ++j) {
      const bf16x8 wf = *(const bf16x8*)&W_lds[j * 16 + l16][k0 + quad * 8];
      acc[j] = MFMA(af, wf, acc[j]);
    }
  }
  #pragma unroll
  for (int j = 0; j < 4; ++j) {
    const int col = colh + j * 16 + l16;
    const float bv = bp[col];
    #pragma unroll
    for (int r = 0; r < 4; ++r)
      outp[(row0 + quad * 4 + r) * 256 + col] = acc[j][r] + bv;
  }
}

// ---------------------------------------------------------------------------
extern "C" void kernel_launch(void* const* d_in, const int* in_sizes, int n_in,
                              void* d_out, int out_size, void* d_ws, size_t ws_size,
                              hipStream_t stream) {
  const float* x0    = (const float*)d_in[0];
  const float* x1    = (const float*)d_in[1];
  const float* Wq    = (const float*)d_in[2];
  const float* Wkv   = (const float*)d_in[3];
  const float* Wproj = (const float*)d_in[4];
  const float* bproj = (const float*)d_in[5];
  const float* Wsr   = (const float*)d_in[6];
  const float* bsr   = (const float*)d_in[7];
  const float* lnw0  = (const float*)d_in[8];
  const float* lnb0  = (const float*)d_in[9];
  const float* lnw1  = (const float*)d_in[10];
  const float* lnb1  = (const float*)d_in[11];

  // d_out (16 MB): [q bf16 8 MB] -> finally y fp32 16 MB (overwrites q after
  // attention has consumed it). ws (14 MB): att 8 | xsb 2 | kbuf 2 | vbuf 2.
  bf16* q_bf   = (bf16*)d_out;
  bf16* att_bf = (bf16*)d_ws;
  bf16* xsb    = att_bf + 4194304;
  bf16* kbuf   = xsb + 1048576;
  bf16* vbuf_t = kbuf + 1048576;
  float* y     = (float*)d_out;

  const dim3 blk(256);
  qc_mfma<<<dim3(320, 4), blk, 0, stream>>>(x0, x1, Wq, Wsr, bsr, q_bf, xsb);
  kvln_mfma<<<dim3(64, 8), blk, 0, stream>>>(xsb, Wkv, lnw0, lnb0, lnw1, lnb1,
                                             kbuf, vbuf_t);
  attn_mfma<<<dim3(32, 32), blk, 0, stream>>>(q_bf, kbuf, vbuf_t, att_bf);
  proj_mfma<<<dim3(256, 4), blk, 0, stream>>>(att_bf, Wproj, bproj, y);
}

// Round 6
// 158.647 us; speedup vs baseline: 1.3649x; 1.3649x over previous
//
#include <hip/hip_runtime.h>
#include <hip/hip_bf16.h>
#include <cstddef>

typedef __hip_bfloat16 bf16;
typedef __attribute__((ext_vector_type(8))) short bf16x8;   // MFMA A/B frag
typedef __attribute__((ext_vector_type(4))) float f32x4;    // MFMA C/D frag
typedef __attribute__((ext_vector_type(4))) short short4v;  // 4x bf16 packed

__device__ __forceinline__ float b2f(bf16 v) { return __bfloat162float(v); }
__device__ __forceinline__ bf16 f2b(float v) { return __float2bfloat16(v); }

#define MFMA(a, b, c) __builtin_amdgcn_mfma_f32_16x16x32_bf16((a), (b), (c), 0, 0, 0)

// Weight layout inside wb (bf16): Wq [0,64K), Wkv [64K,192K), Wp [192K,256K),
// Wsr permuted [256K,512K) with k' = p*256 + c  (p = kh*2+kw).
#define WQ_OFF   0
#define WKV_OFF  65536
#define WP_OFF   196608
#define WSR_OFF  262144

// ---------------------------------------------------------------------------
// Prepass (fused): blocks [0,1024): x0|x1 fp32 -> xb bf16.
//                  blocks [1024,1536): weights fp32 -> wb bf16 (Wsr permuted).
// ---------------------------------------------------------------------------
__global__ __launch_bounds__(256) void prep_cvt(
    const float* __restrict__ x0, const float* __restrict__ x1,
    bf16* __restrict__ xb,
    const float* __restrict__ Wq, const float* __restrict__ Wkv,
    const float* __restrict__ Wp, const float* __restrict__ Wsr,
    bf16* __restrict__ wb) {
  const int t = threadIdx.x;
  if (blockIdx.x < 1024) {
    const int gid = blockIdx.x * 256 + t;             // 262144 threads
    for (int i = gid; i < 1048576; i += 262144) {     // float4 units
      const float4 v = (i < 524288) ? ((const float4*)x0)[i]
                                    : ((const float4*)x1)[i - 524288];
      union { bf16 h[4]; short4v s; } u;
      u.h[0] = f2b(v.x); u.h[1] = f2b(v.y); u.h[2] = f2b(v.z); u.h[3] = f2b(v.w);
      ((short4v*)xb)[i] = u.s;
    }
  } else {
    const int gid = (blockIdx.x - 1024) * 256 + t;    // 131072 threads
    for (int i = gid; i < 524288; i += 131072) {
      float v;
      if (i < WKV_OFF)       v = Wq[i];
      else if (i < WP_OFF)   v = Wkv[i - WKV_OFF];
      else if (i < WSR_OFF)  v = Wp[i - WP_OFF];
      else {
        const int r = i - WSR_OFF;
        const int o = r >> 10, k = r & 1023;
        const int p = k >> 8, c = k & 255;
        v = Wsr[o * 1024 + c * 4 + p];
      }
      wb[i] = f2b(v);
    }
  }
}

// W-tile staging helper: 64 rows x 256 K bf16 (32 KB) into LDS [64][264]
// (pad 264 -> 2-way-free bank reads). Coalesced 16 B per thread.
#define STAGE_W(W_lds, wgl, ldg)                                             \
  _Pragma("unroll")                                                          \
  for (int uu_ = 0; uu_ < 8; ++uu_) {                                        \
    const int idx_ = uu_ * 256 + t;                                          \
    const int wr_ = idx_ >> 5;                                               \
    const int wc_ = (idx_ & 31) * 8;                                         \
    *(bf16x8*)&W_lds[wr_][wc_] = *(const bf16x8*)((wgl) + wr_ * (ldg) + wc_);\
  }

// ---------------------------------------------------------------------------
// Kernel 2 (fused): blocks x<64:  conv as 4 p-passes of 256-K MFMA GEMM
//                                 (scheduled FIRST: long blocks, no tail).
//                   blocks x>=64: q = (xb @ Wq^T) * scale' -> bf16,
//                                 4 row-tiles per block (W staged once).
// grid (128,4) = 512 blocks, 2/CU, load-balanced (conv ~ 4x qproj unit).
// scale' folds log2(e) so attention can use raw v_exp_f32 (exp2).
// ---------------------------------------------------------------------------
__global__ __launch_bounds__(256) void qc_mfma(
    const bf16* __restrict__ xb, const bf16* __restrict__ wb,
    const float* __restrict__ bsr, bf16* __restrict__ q,
    bf16* __restrict__ xsb) {
  __shared__ bf16 W_lds[64][264];
  const int t = threadIdx.x;
  const int wave = t >> 6, lane = t & 63, quad = lane >> 4, l16 = lane & 15;
  const int colh = blockIdx.y * 64;

  if (blockIdx.x < 64) {
    // ---- conv body ----
    const int bx = blockIdx.x;
    const int row0 = bx * 64 + wave * 16;
    const int mrow = row0 + l16;
    const int ab = mrow >> 10;
    const int m = mrow & 1023;
    const int mi_ = m >> 5, mj = m & 31;
    f32x4 acc[4];
    #pragma unroll
    for (int j = 0; j < 4; ++j) acc[j] = (f32x4){0.f, 0.f, 0.f, 0.f};
    for (int p = 0; p < 4; ++p) {
      __syncthreads();   // protect previous pass's W_lds reads
      STAGE_W(W_lds, wb + WSR_OFF + colh * 1024 + p * 256, 1024);
      __syncthreads();
      const int n = (2 * mi_ + (p >> 1)) * 64 + 2 * mj + (p & 1);
      const bf16* ap = xb + (ab * 4096 + n) * 256 + quad * 8;
      #pragma unroll
      for (int c0 = 0; c0 < 256; c0 += 32) {
        const bf16x8 af = *(const bf16x8*)(ap + c0);
        #pragma unroll
        for (int j = 0; j < 4; ++j) {
          const bf16x8 wf = *(const bf16x8*)&W_lds[j * 16 + l16][c0 + quad * 8];
          acc[j] = MFMA(af, wf, acc[j]);
        }
      }
    }
    #pragma unroll
    for (int j = 0; j < 4; ++j) {
      const int col = colh + j * 16 + l16;
      const float bv = bsr[col];
      #pragma unroll
      for (int r = 0; r < 4; ++r)
        xsb[(row0 + quad * 4 + r) * 256 + col] = f2b(acc[j][r] + bv);
    }
  } else {
    // ---- q-projection body: 4 row-tiles per W stage ----
    const int idx = blockIdx.x - 64;          // 0..63
    STAGE_W(W_lds, wb + WQ_OFF + colh * 256, 256);
    __syncthreads();
    const float scale = 0.2550348572f;  // log2(e)/sqrt(32)
    for (int ii = 0; ii < 4; ++ii) {
      const int row0 = (idx * 4 + ii) * 64 + wave * 16;
      const bf16* ap = xb + (row0 + l16) * 256 + quad * 8;
      f32x4 acc[4];
      #pragma unroll
      for (int j = 0; j < 4; ++j) acc[j] = (f32x4){0.f, 0.f, 0.f, 0.f};
      #pragma unroll
      for (int k0 = 0; k0 < 256; k0 += 32) {
        const bf16x8 af = *(const bf16x8*)(ap + k0);
        #pragma unroll
        for (int j = 0; j < 4; ++j) {
          const bf16x8 wf = *(const bf16x8*)&W_lds[j * 16 + l16][k0 + quad * 8];
          acc[j] = MFMA(af, wf, acc[j]);
        }
      }
      #pragma unroll
      for (int j = 0; j < 4; ++j)
        #pragma unroll
        for (int r = 0; r < 4; ++r)
          q[(row0 + quad * 4 + r) * 256 + colh + j * 16 + l16] =
              f2b(acc[j][r] * scale);
    }
  }
}

// ---------------------------------------------------------------------------
// Kernel 3 (fused LN + kv): LayerNorm over C=256 in-register (quad-reduce
// via shfl_xor 16/32), then kv = ln(xsb) @ Wkv^T.
// K-half -> kbuf [abh][m][d]; V-half -> vbuf_t [abh][d][m'] with the bit
// permutation m' = (m&~63) | km(m&63),
//   km(j) = (j&32) | ((j&12)<<1) | ((j&16)>>2) | (j&3),
// so the swapped-QK attention's P fragments are lane-local. grid (64, 8).
// ---------------------------------------------------------------------------
__global__ __launch_bounds__(256) void kvln_mfma(
    const bf16* __restrict__ xsb, const bf16* __restrict__ wb,
    const float* __restrict__ w0, const float* __restrict__ b0,
    const float* __restrict__ w1, const float* __restrict__ b1,
    bf16* __restrict__ kbuf, bf16* __restrict__ vbuf_t) {
  __shared__ bf16 W_lds[64][264];
  __shared__ float lnw[256], lnb[256];
  const int t = threadIdx.x;
  const int wave = t >> 6, lane = t & 63, quad = lane >> 4, l16 = lane & 15;
  const int row0 = blockIdx.x * 64 + wave * 16;
  const int colh = blockIdx.y * 64;     // 0..448 over O=512
  const int a = (blockIdx.x * 64) >> 11;   // block-uniform LN param select
  lnw[t] = a ? w1[t] : w0[t];
  lnb[t] = a ? b1[t] : b0[t];
  STAGE_W(W_lds, wb + WKV_OFF + colh * 256, 256);
  __syncthreads();

  const bf16* ap = xsb + (row0 + l16) * 256 + quad * 8;
  bf16x8 af[8];
  float sum = 0.f, ss = 0.f;
  #pragma unroll
  for (int i = 0; i < 8; ++i) {
    af[i] = *(const bf16x8*)(ap + i * 32);
    #pragma unroll
    for (int e = 0; e < 8; ++e) {
      const float x = b2f(((bf16*)&af[i])[e]);
      sum += x; ss += x * x;
    }
  }
  sum += __shfl_xor(sum, 16, 64); sum += __shfl_xor(sum, 32, 64);
  ss  += __shfl_xor(ss, 16, 64);  ss  += __shfl_xor(ss, 32, 64);
  const float mu = sum * (1.0f / 256.0f);
  const float var = ss * (1.0f / 256.0f) - mu * mu;
  const float rstd = rsqrtf(var + 1e-5f);
  #pragma unroll
  for (int i = 0; i < 8; ++i) {
    const int cb = i * 32 + quad * 8;
    union { bf16 h[8]; bf16x8 v; } u;
    #pragma unroll
    for (int e = 0; e < 8; ++e) {
      const float x = b2f(((bf16*)&af[i])[e]);
      u.h[e] = f2b((x - mu) * rstd * lnw[cb + e] + lnb[cb + e]);
    }
    af[i] = u.v;
  }

  f32x4 acc[4];
  #pragma unroll
  for (int j = 0; j < 4; ++j) acc[j] = (f32x4){0.f, 0.f, 0.f, 0.f};
  #pragma unroll
  for (int i = 0; i < 8; ++i) {
    #pragma unroll
    for (int j = 0; j < 4; ++j) {
      const bf16x8 wf = *(const bf16x8*)&W_lds[j * 16 + l16][i * 32 + quad * 8];
      acc[j] = MFMA(af[i], wf, acc[j]);
    }
  }
  #pragma unroll
  for (int j = 0; j < 4; ++j) {
    const int o = colh + j * 16 + l16;   // 0..511
    #pragma unroll
    for (int r = 0; r < 4; ++r) {
      const int row = row0 + quad * 4 + r;
      const int m = row & 1023;
      const bf16 val = f2b(acc[j][r]);
      if (o < 256) {
        const int h = o >> 5, d = o & 31;
        kbuf[((row >> 10) * 8 + h) * 32768 + m * 32 + d] = val;
      } else {
        const int o2 = o - 256;
        const int h = o2 >> 5, d = o2 & 31;
        const int rr = m & 63;
        const int mp = (m & ~63) | (rr & 32) | ((rr & 12) << 1) |
                       ((rr & 16) >> 2) | (rr & 3);
        vbuf_t[((row >> 10) * 8 + h) * 32768 + d * 1024 + mp] = val;
      }
    }
  }
}

// ---------------------------------------------------------------------------
// Kernel 4: MFMA flash attention, LDS-staged K/V (double-buffered), swapped
// QK^T (S^T = K x Q) with lane-local in-register P -> PV fragments (proven
// round-2 form). q pre-scaled by log2(e)/sqrt(d) -> raw v_exp_f32.
// ---------------------------------------------------------------------------
__global__ __launch_bounds__(256) void attn_mfma(
    const bf16* __restrict__ q, const bf16* __restrict__ kbuf,
    const bf16* __restrict__ vbuf_t, bf16* __restrict__ att) {
  const int abh = blockIdx.y;
  const int ab = abh >> 3;
  const int h = abh & 7;
  const int t = threadIdx.x;
  const int lane = t & 63, quad = lane >> 4, l16 = lane & 15;
  const int qbase = blockIdx.x * 128 + (t >> 6) * 32;

  __shared__ bf16 KT[2][2048];
  __shared__ bf16 VT[2][2048];

  const bf16* kb = kbuf + abh * 32768;
  const bf16* vb = vbuf_t + abh * 32768;

  const int kg = (t >> 6) * 512 + ((t >> 2) & 15) * 32 + (t & 3) * 8;
  const int vg_row = (t >> 7) * 16 + ((t >> 3) & 15);
  const int vg_col = ((t >> 2) & 1) * 32 + (t & 3) * 8;

  bf16x8 qf[2];
  #pragma unroll
  for (int s = 0; s < 2; ++s)
    qf[s] = *(const bf16x8*)(
        q + (ab * 4096 + qbase + s * 16 + l16) * 256 + h * 32 + quad * 8);

  {
    const bf16x8 kr = *(const bf16x8*)(kb + kg);
    const bf16x8 vr = *(const bf16x8*)(vb + vg_row * 1024 + vg_col);
    *(bf16x8*)&KT[0][t * 8] = kr;
    *(bf16x8*)&VT[0][t * 8] = vr;
  }
  __syncthreads();

  f32x4 o[2][2];
  float lp[2] = {0.f, 0.f};
  #pragma unroll
  for (int s = 0; s < 2; ++s) {
    o[s][0] = (f32x4){0.f, 0.f, 0.f, 0.f};
    o[s][1] = (f32x4){0.f, 0.f, 0.f, 0.f};
  }
  const f32x4 zero = {0.f, 0.f, 0.f, 0.f};

  for (int kt = 0; kt < 16; ++kt) {
    const int cur = kt & 1;
    bf16x8 kr, vr;
    const bool pf = (kt + 1 < 16);
    if (pf) {
      const int nk0 = (kt + 1) * 64;
      kr = *(const bf16x8*)(kb + nk0 * 32 + kg);
      vr = *(const bf16x8*)(vb + vg_row * 1024 + nk0 + vg_col);
    }
    // S^T[key][q]: A = K-frag (row=key), B = Q-frag (col=q=l16).
    f32x4 S[2][4];
    #pragma unroll
    for (int tt = 0; tt < 4; ++tt) {
      const bf16x8 kf =
          *(const bf16x8*)&KT[cur][(tt * 64 + l16 * 4 + quad) * 8];
      S[0][tt] = MFMA(kf, qf[0], zero);
      S[1][tt] = MFMA(kf, qf[1], zero);
    }
    // In-register softmax numerator + lane-local PV A-fragments.
    bf16x8 pa[2][2];
    #pragma unroll
    for (int s = 0; s < 2; ++s) {
      float p[4][4];
      float acc = 0.f;
      #pragma unroll
      for (int tt = 0; tt < 4; ++tt)
        #pragma unroll
        for (int r = 0; r < 4; ++r) {
          p[tt][r] = __builtin_amdgcn_exp2f(S[s][tt][r]);
          acc += p[tt][r];
        }
      lp[s] += acc;
      #pragma unroll
      for (int c2 = 0; c2 < 2; ++c2) {
        union { __hip_bfloat162 h2[4]; bf16x8 v; } u;
        u.h2[0] = __float22bfloat162_rn(float2{p[c2 * 2][0], p[c2 * 2][1]});
        u.h2[1] = __float22bfloat162_rn(float2{p[c2 * 2][2], p[c2 * 2][3]});
        u.h2[2] = __float22bfloat162_rn(float2{p[c2 * 2 + 1][0], p[c2 * 2 + 1][1]});
        u.h2[3] = __float22bfloat162_rn(float2{p[c2 * 2 + 1][2], p[c2 * 2 + 1][3]});
        pa[s][c2] = u.v;
      }
    }
    #pragma unroll
    for (int c2 = 0; c2 < 2; ++c2) {
      #pragma unroll
      for (int dh = 0; dh < 2; ++dh) {
        const bf16x8 vf = *(const bf16x8*)&VT[cur]
            [(dh * 128 + l16 * 8 + c2 * 4 + quad) * 8];
        o[0][dh] = MFMA(pa[0][c2], vf, o[0][dh]);
        o[1][dh] = MFMA(pa[1][c2], vf, o[1][dh]);
      }
    }
    if (pf) {
      *(bf16x8*)&KT[cur ^ 1][t * 8] = kr;
      *(bf16x8*)&VT[cur ^ 1][t * 8] = vr;
    }
    __syncthreads();
  }
  // Denominator: sum across quads (lane ^16, ^32), broadcast, normalize.
  #pragma unroll
  for (int s = 0; s < 2; ++s) {
    lp[s] += __shfl_xor(lp[s], 16, 64);
    lp[s] += __shfl_xor(lp[s], 32, 64);
  }
  #pragma unroll
  for (int s = 0; s < 2; ++s) {
    #pragma unroll
    for (int r = 0; r < 4; ++r) {
      const float li = __shfl(lp[s], quad * 4 + r, 16);
      const float inv = 1.0f / li;
      const int qrow = ab * 4096 + qbase + s * 16 + quad * 4 + r;
      bf16* orow = att + qrow * 256 + h * 32;
      orow[l16]      = f2b(o[s][0][r] * inv);
      orow[16 + l16] = f2b(o[s][1][r] * inv);
    }
  }
}

// ---------------------------------------------------------------------------
// Kernel 5: y = att @ Wproj^T + bproj -> fp32 d_out. 2 row-tiles per W
// stage. grid (128, 4) = 512 blocks, 2/CU.
// ---------------------------------------------------------------------------
__global__ __launch_bounds__(256) void proj_mfma(
    const bf16* __restrict__ att, const bf16* __restrict__ wb,
    const float* __restrict__ bp, float* __restrict__ outp) {
  __shared__ bf16 W_lds[64][264];
  const int t = threadIdx.x;
  const int wave = t >> 6, lane = t & 63, quad = lane >> 4, l16 = lane & 15;
  const int colh = blockIdx.y * 64;
  STAGE_W(W_lds, wb + WP_OFF + colh * 256, 256);
  __syncthreads();
  for (int ii = 0; ii < 2; ++ii) {
    const int row0 = (blockIdx.x * 2 + ii) * 64 + wave * 16;
    const bf16* ap = att + (row0 + l16) * 256 + quad * 8;
    f32x4 acc[4];
    #pragma unroll
    for (int j = 0; j < 4; ++j) acc[j] = (f32x4){0.f, 0.f, 0.f, 0.f};
    #pragma unroll
    for (int k0 = 0; k0 < 256; k0 += 32) {
      const bf16x8 af = *(const bf16x8*)(ap + k0);
      #pragma unroll
      for (int j = 0; j < 4; ++j) {
        const bf16x8 wf = *(const bf16x8*)&W_lds[j * 16 + l16][k0 + quad * 8];
        acc[j] = MFMA(af, wf, acc[j]);
      }
    }
    #pragma unroll
    for (int j = 0; j < 4; ++j) {
      const int col = colh + j * 16 + l16;
      const float bv = bp[col];
      #pragma unroll
      for (int r = 0; r < 4; ++r)
        outp[(row0 + quad * 4 + r) * 256 + col] = acc[j][r] + bv;
    }
  }
}

// ---------------------------------------------------------------------------
extern "C" void kernel_launch(void* const* d_in, const int* in_sizes, int n_in,
                              void* d_out, int out_size, void* d_ws, size_t ws_size,
                              hipStream_t stream) {
  const float* x0    = (const float*)d_in[0];
  const float* x1    = (const float*)d_in[1];
  const float* Wq    = (const float*)d_in[2];
  const float* Wkv   = (const float*)d_in[3];
  const float* Wproj = (const float*)d_in[4];
  const float* bproj = (const float*)d_in[5];
  const float* Wsr   = (const float*)d_in[6];
  const float* bsr   = (const float*)d_in[7];
  const float* lnw0  = (const float*)d_in[8];
  const float* lnb0  = (const float*)d_in[9];
  const float* lnw1  = (const float*)d_in[10];
  const float* lnb1  = (const float*)d_in[11];

  // d_out (16 MB): [q bf16 8 MB][xb bf16 8 MB] -> finally y fp32 16 MB.
  // ws (15 MB): att 8 | xsb 2 | kbuf 2 | vbuf_t 2 | wb 1.
  bf16* q_bf   = (bf16*)d_out;
  bf16* xb     = q_bf + 4194304;
  bf16* att_bf = (bf16*)d_ws;
  bf16* xsb    = att_bf + 4194304;
  bf16* kbuf   = xsb + 1048576;
  bf16* vbuf_t = kbuf + 1048576;
  bf16* wb     = vbuf_t + 1048576;
  float* y     = (float*)d_out;

  const dim3 blk(256);
  prep_cvt<<<dim3(1536), blk, 0, stream>>>(x0, x1, xb, Wq, Wkv, Wproj, Wsr, wb);
  qc_mfma<<<dim3(128, 4), blk, 0, stream>>>(xb, wb, bsr, q_bf, xsb);
  kvln_mfma<<<dim3(64, 8), blk, 0, stream>>>(xsb, wb, lnw0, lnb0, lnw1, lnb1,
                                             kbuf, vbuf_t);
  attn_mfma<<<dim3(32, 32), blk, 0, stream>>>(q_bf, kbuf, vbuf_t, att_bf);
  proj_mfma<<<dim3(128, 4), blk, 0, stream>>>(att_bf, wb, bproj, y);
}